// Round 2
// baseline (181.863 us; speedup 1.0000x reference)
//
#include <hip/hip_runtime.h>
#include <stdint.h>

// ---------------------------------------------------------------------------
// Head: out = softmax((x Wq)(x Wk)^T / 8) (x Wv)
// B=8, T=2048, C=512, D=64.  ALL I/O IS FP32 (per reference file).
// Internals: bf16 MFMA with fp32 accumulation.
//
// Workspace (bf16):
//   qg [16384][64]        (token-major)  -> Q b-frags contiguous
//   kg [16384][64]        (token-major)  -> K a-frags contiguous
//   vT [8][64][2048]      (d-major)      -> V a-frags contiguous
//   Wt [3][64][512]       (w0=Wq w1=Wk w2=Wv, transposed, bf16)
//
// MFMA 16x16x32 bf16 fragment maps (gfx950, m89/m91/m120-verified):
//   A: lane holds A[m=lane&15][k=quad*8+j]   (quad=lane>>4, j=0..7)
//   B: lane holds B[k=quad*8+j][n=lane&15]
//   D: lane holds D[row=quad*4+r][col=lane&15] (r=reg 0..3)
// ---------------------------------------------------------------------------

typedef short bf16x8 __attribute__((ext_vector_type(8)));
typedef float f32x4 __attribute__((ext_vector_type(4)));

#define MFMA_BF16 __builtin_amdgcn_mfma_f32_16x16x32_bf16

__device__ __forceinline__ unsigned int f32_to_bf16_bits(float f) {
    union { float f; unsigned int u; } v; v.f = f;
    return (v.u + 0x7FFFu + ((v.u >> 16) & 1u)) >> 16;   // RNE
}

__device__ __forceinline__ uint2 pack4_bf16(float a, float b, float c, float d) {
    uint2 r;
    r.x = f32_to_bf16_bits(a) | (f32_to_bf16_bits(b) << 16);
    r.y = f32_to_bf16_bits(c) | (f32_to_bf16_bits(d) << 16);
    return r;
}

__device__ __forceinline__ bf16x8 to_bf16x8(f32x4 a, f32x4 b) {
    bf16x8 r;
    r[0] = (short)f32_to_bf16_bits(a[0]);
    r[1] = (short)f32_to_bf16_bits(a[1]);
    r[2] = (short)f32_to_bf16_bits(a[2]);
    r[3] = (short)f32_to_bf16_bits(a[3]);
    r[4] = (short)f32_to_bf16_bits(b[0]);
    r[5] = (short)f32_to_bf16_bits(b[1]);
    r[6] = (short)f32_to_bf16_bits(b[2]);
    r[7] = (short)f32_to_bf16_bits(b[3]);
    return r;
}

// ---------------------------------------------------------------------------
// Kernel 0: weights fp32 -> Wt bf16 [3][64][512]; w0=Wq, w1=Wk, w2=Wv
// ---------------------------------------------------------------------------
__global__ void wt_kernel(const float* __restrict__ Wq,
                          const float* __restrict__ Wk,
                          const float* __restrict__ Wv,
                          unsigned short* __restrict__ Wt)
{
    int idx = blockIdx.x * 256 + threadIdx.x;   // exactly 3*64*512 threads
    int w = idx >> 15;          // / (64*512)
    int r = idx & 32767;
    int n = r >> 9;             // / 512
    int c = r & 511;
    const float* src = (w == 0) ? Wq : ((w == 1) ? Wk : Wv);
    Wt[idx] = (unsigned short)f32_to_bf16_bits(src[c * 64 + n]);
}

// ---------------------------------------------------------------------------
// Kernel 1: projections.  OUT^T = Wt · x^T  (per wave: 16 tokens x 192 outs)
//   A-frag = Wt rows (bf16, L1/L2 resident, shared by all waves)
//   B-frag = x rows (fp32 -> bf16 convert; x read exactly once from HBM)
// 256 blocks x 256 threads.
// ---------------------------------------------------------------------------
__global__ __launch_bounds__(256, 1) void proj_kernel(
    const float* __restrict__ x, const unsigned short* __restrict__ Wt,
    unsigned short* __restrict__ qg, unsigned short* __restrict__ kg,
    unsigned short* __restrict__ vT)
{
    const int lane = threadIdx.x & 63;
    const int wave = threadIdx.x >> 6;
    const int c    = lane & 15;
    const int quad = lane >> 4;
    const int t0   = blockIdx.x * 64 + wave * 16;

    f32x4 acc[12];
    #pragma unroll
    for (int i = 0; i < 12; i++) acc[i] = f32x4{0.f, 0.f, 0.f, 0.f};

    const float*          xrow = x  + (size_t)(t0 + c) * 512 + quad * 8;
    const unsigned short* wrow = Wt + (size_t)c * 512 + quad * 8;

    #pragma unroll 2
    for (int ks = 0; ks < 16; ks++) {
        f32x4 xa = *(const f32x4*)(xrow + ks * 32);
        f32x4 xbb = *(const f32x4*)(xrow + ks * 32 + 4);
        bf16x8 xb = to_bf16x8(xa, xbb);
        #pragma unroll
        for (int mt = 0; mt < 12; mt++) {
            bf16x8 wa = *(const bf16x8*)(wrow + (size_t)mt * (16 * 512) + ks * 32);
            acc[mt] = MFMA_BF16(wa, xb, acc[mt], 0, 0, 0);
        }
    }

    const int b   = t0 >> 11;            // batch
    const int tl  = (t0 & 2047) + c;     // batch-local token
    const int tg  = t0 + c;              // global token

    #pragma unroll
    for (int mt = 0; mt < 12; mt++) {
        const int w  = mt >> 2;                       // 0:q 1:k 2:v
        const int nn = (mt & 3) * 16 + quad * 4;      // out-dim base (0..60)
        if (w < 2) {
            unsigned short* dst = (w == 0 ? qg : kg) + (size_t)tg * 64 + nn;
            *(uint2*)dst = pack4_bf16(acc[mt][0], acc[mt][1], acc[mt][2], acc[mt][3]);
        } else {
            unsigned short* dst = vT + (size_t)b * (64 * 2048) + (size_t)nn * 2048 + tl;
            dst[0]    = (unsigned short)f32_to_bf16_bits(acc[mt][0]);
            dst[2048] = (unsigned short)f32_to_bf16_bits(acc[mt][1]);
            dst[4096] = (unsigned short)f32_to_bf16_bits(acc[mt][2]);
            dst[6144] = (unsigned short)f32_to_bf16_bits(acc[mt][3]);
        }
    }
}

// ---------------------------------------------------------------------------
// Kernel 2: flash attention, transposed-S formulation.  fp32 output.
//   per wave: 16 q-rows, loop over 16 key-tiles of 128.
//   S^T = K·Q^T  (D: row=key, col=q)  -> softmax reductions mostly lane-local
//   P^T packed to wave-private LDS with 8B writes; O^T = V^T·P^T.
// No __syncthreads (wave-private LDS); compiler fences order the round-trip.
// ---------------------------------------------------------------------------
__global__ __launch_bounds__(256, 1) void attn_kernel(
    const unsigned short* __restrict__ qg, const unsigned short* __restrict__ kg,
    const unsigned short* __restrict__ vT, float* __restrict__ out)
{
    __shared__ unsigned short pt[4][16 * 136];   // per-wave P [q=16][key=128], ld=136
    const int lane = threadIdx.x & 63;
    const int wave = threadIdx.x >> 6;
    const int c    = lane & 15;
    const int quad = lane >> 4;
    const int t0   = blockIdx.x * 64 + wave * 16;
    const int b    = t0 >> 11;

    unsigned short* ptw = &pt[wave][0];
    const unsigned short* kbp = kg + (size_t)b * (2048 * 64) + (size_t)c * 64 + quad * 8;
    const unsigned short* vbp = vT + (size_t)b * (64 * 2048) + (size_t)c * 2048 + quad * 8;

    // Q b-frags: B[k=d][n=q]
    bf16x8 qb0 = *(const bf16x8*)(qg + (size_t)(t0 + c) * 64 + quad * 8);
    bf16x8 qb1 = *(const bf16x8*)(qg + (size_t)(t0 + c) * 64 + 32 + quad * 8);

    f32x4 o0 = {0,0,0,0}, o1 = {0,0,0,0}, o2 = {0,0,0,0}, o3 = {0,0,0,0};
    float m_run = -1e30f, l_run = 0.f;
    const float cexp = 0.18033688011112042f;   // log2(e)/8  (scores = raw/8)

    for (int kt = 0; kt < 16; kt++) {
        const int key0 = kt * 128;

        // ---- K a-frags: A[m=key][k=d], contiguous ----
        bf16x8 ka[8][2];
        #pragma unroll
        for (int mt = 0; mt < 8; mt++) {
            const unsigned short* kp = kbp + (size_t)(key0 + mt * 16) * 64;
            ka[mt][0] = *(const bf16x8*)kp;
            ka[mt][1] = *(const bf16x8*)(kp + 32);
        }

        // ---- S^T = K·Q^T ----
        f32x4 st[8];
        const f32x4 z = {0,0,0,0};
        #pragma unroll
        for (int mt = 0; mt < 8; mt++) {
            st[mt] = MFMA_BF16(ka[mt][0], qb0, z, 0, 0, 0);
            st[mt] = MFMA_BF16(ka[mt][1], qb1, st[mt], 0, 0, 0);
        }

        // ---- issue V a-frag loads early (overlap with softmax VALU) ----
        bf16x8 va[4][4];
        #pragma unroll
        for (int ks = 0; ks < 4; ks++) {
            #pragma unroll
            for (int mt = 0; mt < 4; mt++)
                va[ks][mt] = *(const bf16x8*)(vbp + (size_t)mt * (16 * 2048) + key0 + ks * 32);
        }

        // ---- online softmax over keys (per column c = q index) ----
        float mx = -1e30f;
        #pragma unroll
        for (int mt = 0; mt < 8; mt++)
            mx = fmaxf(mx, fmaxf(fmaxf(st[mt][0], st[mt][1]), fmaxf(st[mt][2], st[mt][3])));
        mx = fmaxf(mx, __shfl_xor(mx, 16));
        mx = fmaxf(mx, __shfl_xor(mx, 32));
        const float m_new = fmaxf(m_run, mx);
        const float alpha = exp2f((m_run - m_new) * cexp);

        asm volatile("" ::: "memory");   // order: P writes below stay below
        float ls = 0.f;
        #pragma unroll
        for (int mt = 0; mt < 8; mt++) {
            float p0 = exp2f((st[mt][0] - m_new) * cexp);
            float p1 = exp2f((st[mt][1] - m_new) * cexp);
            float p2 = exp2f((st[mt][2] - m_new) * cexp);
            float p3 = exp2f((st[mt][3] - m_new) * cexp);
            ls += (p0 + p1) + (p2 + p3);
            // P[q=c][key = mt*16 + quad*4 + r]  -> one 8B write
            *(uint2*)(ptw + c * 136 + mt * 16 + quad * 4) = pack4_bf16(p0, p1, p2, p3);
        }
        asm volatile("" ::: "memory");   // all P writes issued before P reads
        ls += __shfl_xor(ls, 16);
        ls += __shfl_xor(ls, 32);

        o0 *= alpha; o1 *= alpha; o2 *= alpha; o3 *= alpha;
        l_run = l_run * alpha + ls;
        m_run = m_new;

        // ---- O^T += V^T · P^T ----
        #pragma unroll
        for (int ks = 0; ks < 4; ks++) {
            bf16x8 pb = *(const bf16x8*)(ptw + c * 136 + ks * 32 + quad * 8);
            o0 = MFMA_BF16(va[ks][0], pb, o0, 0, 0, 0);
            o1 = MFMA_BF16(va[ks][1], pb, o1, 0, 0, 0);
            o2 = MFMA_BF16(va[ks][2], pb, o2, 0, 0, 0);
            o3 = MFMA_BF16(va[ks][3], pb, o3, 0, 0, 0);
        }
        asm volatile("" ::: "memory");   // P reads done before next tile's writes
    }

    const float rl = 1.f / l_run;
    o0 *= rl; o1 *= rl; o2 *= rl; o3 *= rl;
    // O^T D-layout: row = d = mt*16 + quad*4 + r, col = q = c -> out[t][d] fp32
    float* op = out + (size_t)(t0 + c) * 64 + quad * 4;
    *(f32x4*)(op)      = o0;
    *(f32x4*)(op + 16) = o1;
    *(f32x4*)(op + 32) = o2;
    *(f32x4*)(op + 48) = o3;
}

// ---------------------------------------------------------------------------
extern "C" void kernel_launch(void* const* d_in, const int* in_sizes, int n_in,
                              void* d_out, int out_size, void* d_ws, size_t ws_size,
                              hipStream_t stream)
{
    const float* x  = (const float*)d_in[0];
    const float* Wk = (const float*)d_in[1];
    const float* Wq = (const float*)d_in[2];
    const float* Wv = (const float*)d_in[3];
    float* out = (float*)d_out;

    char* ws = (char*)d_ws;
    unsigned short* qg = (unsigned short*)(ws);                  // 2 MiB
    unsigned short* kg = (unsigned short*)(ws + (2u << 20));     // 2 MiB
    unsigned short* vT = (unsigned short*)(ws + (4u << 20));     // 2 MiB
    unsigned short* Wt = (unsigned short*)(ws + (6u << 20));     // 192 KiB

    hipLaunchKernelGGL(wt_kernel,   dim3(384), dim3(256), 0, stream, Wq, Wk, Wv, Wt);
    hipLaunchKernelGGL(proj_kernel, dim3(256), dim3(256), 0, stream, x, Wt, qg, kg, vT);
    hipLaunchKernelGGL(attn_kernel, dim3(256), dim3(256), 0, stream, qg, kg, vT, out);
}